// Round 5
// baseline (261.944 us; speedup 1.0000x reference)
//
#include <hip/hip_runtime.h>
#include <math.h>

#define EPS 1e-8f
#define HALF_BIN 0.05f

// clang ext-vector so __builtin_nontemporal_load is legal (HIP float4 is a
// struct; the builtin requires scalar/vector type).
typedef float v4f __attribute__((ext_vector_type(4)));

__device__ __forceinline__ v4f ntload4(const v4f* p) {
    return __builtin_nontemporal_load(p);
}

// pd = sigmoid(xu) - sigmoid(xl), xu >= xl, computed with one reciprocal:
//   e_u = exp(-xu), e_l = exp(-xl)
//   pd  = (e_l - e_u) / ((1+e_u)(1+e_l))
// exp args clamped to <= 87 so e is finite; saturated cases give den->inf ->
// rcp 0 -> pd 0, matching the reference's (0 - 0) there.
__device__ __forceinline__ float sigmoid_diff(float xu, float xl) {
    float eu = __expf(fminf(-xu, 87.0f));
    float el = __expf(fminf(-xl, 87.0f));
    float num = el - eu;
    float den = (1.0f + eu) * (1.0f + el);
    return __fdividef(num, den);
}

// buf layout per group: [0]=p, [1]=tv, then for k: [2+3k]=mu, [3+3k]=sigma, [4+3k]=weight
template <int K>
__device__ __forceinline__ void process_group_buf(
    const v4f (&buf)[3 * K + 2],
    float& bce, float& ll, float& npaid)
{
    float pv[4] = {buf[0].x, buf[0].y, buf[0].z, buf[0].w};
    float t [4] = {buf[1].x, buf[1].y, buf[1].z, buf[1].w};
    float lik[4] = {0.0f, 0.0f, 0.0f, 0.0f};

    #pragma unroll
    for (int k = 0; k < K; ++k) {
        const v4f mf = buf[2 + 3 * k];
        const v4f sf = buf[3 + 3 * k];
        const v4f wf = buf[4 + 3 * k];
        float m[4] = {mf.x, mf.y, mf.z, mf.w};
        float s[4] = {sf.x, sf.y, sf.z, sf.w};
        float w[4] = {wf.x, wf.y, wf.z, wf.w};
        #pragma unroll
        for (int j = 0; j < 4; ++j) {
            float inv_s = __fdividef(1.0f, s[j] + EPS);
            float xu = (t[j] + HALF_BIN - m[j]) * inv_s;
            float xl = (t[j] - HALF_BIN - m[j]) * inv_s;
            float pd = fmaxf(sigmoid_diff(xu, xl), EPS);
            lik[j] = fmaf(w[j], pd, lik[j]);
        }
    }

    #pragma unroll
    for (int j = 0; j < 4; ++j) {
        bool paid = t[j] > 0.0f;
        float val = paid ? pv[j] : (1.0f - pv[j]);
        bce -= fmaxf(__logf(val), -100.0f);
        float lg = __logf(lik[j] + EPS);
        ll    += paid ? lg : 0.0f;
        npaid += paid ? 1.0f : 0.0f;
    }
}

template <int K>
__device__ __forceinline__ void process_elem(
    float pv, float t, const float* mu, const float* sigma, const float* weight,
    size_t i, size_t B, float& bce, float& ll, float& npaid)
{
    float lik = 0.0f;
    #pragma unroll
    for (int k = 0; k < K; ++k) {
        size_t off = (size_t)k * B + i;
        float inv_s = __fdividef(1.0f, sigma[off] + EPS);
        float xu = (t + HALF_BIN - mu[off]) * inv_s;
        float xl = (t - HALF_BIN - mu[off]) * inv_s;
        float pd = fmaxf(sigmoid_diff(xu, xl), EPS);
        lik = fmaf(weight[off], pd, lik);
    }
    bool paid = t > 0.0f;
    float val = paid ? pv : (1.0f - pv);
    bce -= fmaxf(__logf(val), -100.0f);
    float lg = __logf(lik + EPS);
    ll    += paid ? lg : 0.0f;
    npaid += paid ? 1.0f : 0.0f;
}

// R5: main loop byte-identical to R4 (nt loads + 2048 blocks, main <40us).
// Change: the separate zimol_reduce launch is fused in via last-block ticket.
// XCD-coherence discipline (G16): partials published with device-scope
// atomicExch (not plain stores), ticket after __threadfence(); last block
// re-reads partials with atomicAdd(p, 0.0f) — a coherent RMW read that cannot
// hit a stale per-XCD L2 line. Final reduce in double, as before.
template <int K>
__global__ __launch_bounds__(256, 4) void zimol_main(
    const float* __restrict__ p,
    const float* __restrict__ mu,
    const float* __restrict__ sigma,
    const float* __restrict__ weight,
    const float* __restrict__ tv,
    float* __restrict__ part_bce,
    float* __restrict__ part_ll,
    float* __restrict__ part_n,
    unsigned int* __restrict__ ticket,
    float* __restrict__ out,
    int B)
{
    const int tid    = blockIdx.x * blockDim.x + threadIdx.x;
    const int stride = gridDim.x * blockDim.x;

    float bce = 0.0f, ll = 0.0f, npaid = 0.0f;

    if ((B & 3) == 0) {
        const int B4 = B >> 2;
        const v4f* __restrict__ p4  = (const v4f*)p;
        const v4f* __restrict__ tv4 = (const v4f*)tv;
        const v4f* __restrict__ mu4 = (const v4f*)mu;
        const v4f* __restrict__ sg4 = (const v4f*)sigma;
        const v4f* __restrict__ wt4 = (const v4f*)weight;

        constexpr int NB = 3 * K + 2;   // v4f's per group
        int i = tid;
        // two independent groups per trip; all 2*NB loads issued before compute
        for (; i + stride < B4; i += 2 * stride) {
            v4f buf[2][NB];
            #pragma unroll
            for (int u = 0; u < 2; ++u) {
                const int idx = i + u * stride;
                buf[u][0] = ntload4(p4  + idx);
                buf[u][1] = ntload4(tv4 + idx);
                #pragma unroll
                for (int k = 0; k < K; ++k) {
                    const size_t off = (size_t)k * (size_t)B4;
                    buf[u][2 + 3 * k] = ntload4(mu4 + off + idx);
                    buf[u][3 + 3 * k] = ntload4(sg4 + off + idx);
                    buf[u][4 + 3 * k] = ntload4(wt4 + off + idx);
                }
            }
            process_group_buf<K>(buf[0], bce, ll, npaid);
            process_group_buf<K>(buf[1], bce, ll, npaid);
        }
        // remaining single groups
        for (; i < B4; i += stride) {
            v4f buf[NB];
            buf[0] = ntload4(p4  + i);
            buf[1] = ntload4(tv4 + i);
            #pragma unroll
            for (int k = 0; k < K; ++k) {
                const size_t off = (size_t)k * (size_t)B4;
                buf[2 + 3 * k] = ntload4(mu4 + off + i);
                buf[3 + 3 * k] = ntload4(sg4 + off + i);
                buf[4 + 3 * k] = ntload4(wt4 + off + i);
            }
            process_group_buf<K>(buf, bce, ll, npaid);
        }
    } else {
        for (int i = tid; i < B; i += stride) {
            process_elem<K>(p[i], tv[i], mu, sigma, weight,
                            (size_t)i, (size_t)B, bce, ll, npaid);
        }
    }

    // wave-level reduction (wave = 64 lanes)
    #pragma unroll
    for (int off = 32; off > 0; off >>= 1) {
        bce   += __shfl_down(bce,   off, 64);
        ll    += __shfl_down(ll,    off, 64);
        npaid += __shfl_down(npaid, off, 64);
    }

    __shared__ float sdata[3][4];
    __shared__ unsigned int s_rank;
    const int wave = threadIdx.x >> 6;
    const int lane = threadIdx.x & 63;
    if (lane == 0) {
        sdata[0][wave] = bce;
        sdata[1][wave] = ll;
        sdata[2][wave] = npaid;
    }
    __syncthreads();
    if (threadIdx.x == 0) {
        float b = 0.0f, l = 0.0f, n = 0.0f;
        #pragma unroll
        for (int w = 0; w < 4; ++w) {
            b += sdata[0][w];
            l += sdata[1][w];
            n += sdata[2][w];
        }
        // device-scope publication of this block's partials
        atomicExch(&part_bce[blockIdx.x], b);
        atomicExch(&part_ll [blockIdx.x], l);
        atomicExch(&part_n  [blockIdx.x], n);
        __threadfence();                      // drain before taking the ticket
        s_rank = atomicAdd(ticket, 1u);
    }
    __syncthreads();
    if (s_rank != (unsigned int)gridDim.x - 1u) return;

    // ---- last block: final reduction (replaces zimol_reduce) ----
    double db = 0.0, dl = 0.0, dn = 0.0;
    for (int i = threadIdx.x; i < (int)gridDim.x; i += blockDim.x) {
        db += (double)atomicAdd(&part_bce[i], 0.0f);   // coherent RMW read
        dl += (double)atomicAdd(&part_ll [i], 0.0f);
        dn += (double)atomicAdd(&part_n  [i], 0.0f);
    }
    #pragma unroll
    for (int off = 32; off > 0; off >>= 1) {
        db += __shfl_down(db, off, 64);
        dl += __shfl_down(dl, off, 64);
        dn += __shfl_down(dn, off, 64);
    }
    __shared__ double sdd[3][4];
    if (lane == 0) {
        sdd[0][wave] = db;
        sdd[1][wave] = dl;
        sdd[2][wave] = dn;
    }
    __syncthreads();
    if (threadIdx.x == 0) {
        double tb = 0.0, tl = 0.0, tn = 0.0;
        #pragma unroll
        for (int w = 0; w < 4; ++w) {
            tb += sdd[0][w];
            tl += sdd[1][w];
            tn += sdd[2][w];
        }
        double purchase = tb / (double)B;
        double ltv = (tn > 0.0) ? -(tl / fmax(tn, 1.0)) : 0.0;
        out[0] = (float)(purchase + ltv);
    }
}

extern "C" void kernel_launch(void* const* d_in, const int* in_sizes, int n_in,
                              void* d_out, int out_size, void* d_ws, size_t ws_size,
                              hipStream_t stream) {
    const float* p      = (const float*)d_in[0];
    const float* mu     = (const float*)d_in[1];
    const float* sigma  = (const float*)d_in[2];
    const float* weight = (const float*)d_in[3];
    const float* tv     = (const float*)d_in[4];
    float* out = (float*)d_out;

    const int B = in_sizes[0];
    const int K = in_sizes[1] / B;

    const int threads = 256;
    // 2048 blocks (R4 config: nt regime wants the waves; each thread runs
    // exactly one trip of the 2-way-ILP loop).
    int work = ((B + 3) >> 2);
    int blocks = (work + threads - 1) / threads;
    if (blocks > 2048) blocks = 2048;
    if (blocks < 1) blocks = 1;

    float* part_bce = (float*)d_ws;
    float* part_ll  = part_bce + blocks;
    float* part_n   = part_ll  + blocks;
    unsigned int* ticket = (unsigned int*)(part_n + blocks);

    // zero the ticket (graph-capture-safe, stream-ordered; ~0 cost dispatch)
    hipMemsetAsync(ticket, 0, sizeof(unsigned int), stream);

    if (K == 3) {
        zimol_main<3><<<blocks, threads, 0, stream>>>(p, mu, sigma, weight, tv,
            part_bce, part_ll, part_n, ticket, out, B);
    } else if (K == 1) {
        zimol_main<1><<<blocks, threads, 0, stream>>>(p, mu, sigma, weight, tv,
            part_bce, part_ll, part_n, ticket, out, B);
    } else if (K == 2) {
        zimol_main<2><<<blocks, threads, 0, stream>>>(p, mu, sigma, weight, tv,
            part_bce, part_ll, part_n, ticket, out, B);
    } else {
        zimol_main<4><<<blocks, threads, 0, stream>>>(p, mu, sigma, weight, tv,
            part_bce, part_ll, part_n, ticket, out, B);
    }
}

// Round 6
// 177.276 us; speedup vs baseline: 1.4776x; 1.4776x over previous
//
#include <hip/hip_runtime.h>
#include <math.h>

#define EPS 1e-8f
#define HALF_BIN 0.05f

// clang ext-vector so __builtin_nontemporal_load is legal (HIP float4 is a
// struct; the builtin requires scalar/vector type).
typedef float v4f __attribute__((ext_vector_type(4)));

__device__ __forceinline__ v4f ntload4(const v4f* p) {
    return __builtin_nontemporal_load(p);
}

// pd = sigmoid(xu) - sigmoid(xl), xu >= xl, computed with one reciprocal:
//   e_u = exp(-xu), e_l = exp(-xl)
//   pd  = (e_l - e_u) / ((1+e_u)(1+e_l))
// exp args clamped to <= 87 so e is finite; saturated cases give den->inf ->
// rcp 0 -> pd 0, matching the reference's (0 - 0) there.
__device__ __forceinline__ float sigmoid_diff(float xu, float xl) {
    float eu = __expf(fminf(-xu, 87.0f));
    float el = __expf(fminf(-xl, 87.0f));
    float num = el - eu;
    float den = (1.0f + eu) * (1.0f + el);
    return __fdividef(num, den);
}

// buf layout per group: [0]=p, [1]=tv, then for k: [2+3k]=mu, [3+3k]=sigma, [4+3k]=weight
template <int K>
__device__ __forceinline__ void process_group_buf(
    const v4f (&buf)[3 * K + 2],
    float& bce, float& ll, float& npaid)
{
    float pv[4] = {buf[0].x, buf[0].y, buf[0].z, buf[0].w};
    float t [4] = {buf[1].x, buf[1].y, buf[1].z, buf[1].w};
    float lik[4] = {0.0f, 0.0f, 0.0f, 0.0f};

    #pragma unroll
    for (int k = 0; k < K; ++k) {
        const v4f mf = buf[2 + 3 * k];
        const v4f sf = buf[3 + 3 * k];
        const v4f wf = buf[4 + 3 * k];
        float m[4] = {mf.x, mf.y, mf.z, mf.w};
        float s[4] = {sf.x, sf.y, sf.z, sf.w};
        float w[4] = {wf.x, wf.y, wf.z, wf.w};
        #pragma unroll
        for (int j = 0; j < 4; ++j) {
            float inv_s = __fdividef(1.0f, s[j] + EPS);
            float xu = (t[j] + HALF_BIN - m[j]) * inv_s;
            float xl = (t[j] - HALF_BIN - m[j]) * inv_s;
            float pd = fmaxf(sigmoid_diff(xu, xl), EPS);
            lik[j] = fmaf(w[j], pd, lik[j]);
        }
    }

    #pragma unroll
    for (int j = 0; j < 4; ++j) {
        bool paid = t[j] > 0.0f;
        float val = paid ? pv[j] : (1.0f - pv[j]);
        bce -= fmaxf(__logf(val), -100.0f);
        float lg = __logf(lik[j] + EPS);
        ll    += paid ? lg : 0.0f;
        npaid += paid ? 1.0f : 0.0f;
    }
}

template <int K>
__device__ __forceinline__ void process_elem(
    float pv, float t, const float* mu, const float* sigma, const float* weight,
    size_t i, size_t B, float& bce, float& ll, float& npaid)
{
    float lik = 0.0f;
    #pragma unroll
    for (int k = 0; k < K; ++k) {
        size_t off = (size_t)k * B + i;
        float inv_s = __fdividef(1.0f, sigma[off] + EPS);
        float xu = (t + HALF_BIN - mu[off]) * inv_s;
        float xl = (t - HALF_BIN - mu[off]) * inv_s;
        float pd = fmaxf(sigmoid_diff(xu, xl), EPS);
        lik = fmaf(weight[off], pd, lik);
    }
    bool paid = t > 0.0f;
    float val = paid ? pv : (1.0f - pv);
    bce -= fmaxf(__logf(val), -100.0f);
    float lg = __logf(lik + EPS);
    ll    += paid ? lg : 0.0f;
    npaid += paid ? 1.0f : 0.0f;
}

// R6: exact revert to R3 (best graded: 176.9us; nt loads, 1024 blocks,
// separate reduce kernel). R5's in-kernel fused reduction (ticket atomics +
// threadfence + cross-XCD RMW reads) cost +90us on the main dispatch —
// kernel-boundary coherence via a second tiny launch is strictly cheaper
// than grid-wide device-scope atomic protocols on 8 non-coherent XCDs.
template <int K>
__global__ __launch_bounds__(256, 4) void zimol_main(
    const float* __restrict__ p,
    const float* __restrict__ mu,
    const float* __restrict__ sigma,
    const float* __restrict__ weight,
    const float* __restrict__ tv,
    float* __restrict__ part_bce,
    float* __restrict__ part_ll,
    float* __restrict__ part_n,
    int B)
{
    const int tid    = blockIdx.x * blockDim.x + threadIdx.x;
    const int stride = gridDim.x * blockDim.x;

    float bce = 0.0f, ll = 0.0f, npaid = 0.0f;

    if ((B & 3) == 0) {
        const int B4 = B >> 2;
        const v4f* __restrict__ p4  = (const v4f*)p;
        const v4f* __restrict__ tv4 = (const v4f*)tv;
        const v4f* __restrict__ mu4 = (const v4f*)mu;
        const v4f* __restrict__ sg4 = (const v4f*)sigma;
        const v4f* __restrict__ wt4 = (const v4f*)weight;

        constexpr int NB = 3 * K + 2;   // v4f's per group
        int i = tid;
        // two independent groups per trip; all 2*NB loads issued before compute
        for (; i + stride < B4; i += 2 * stride) {
            v4f buf[2][NB];
            #pragma unroll
            for (int u = 0; u < 2; ++u) {
                const int idx = i + u * stride;
                buf[u][0] = ntload4(p4  + idx);
                buf[u][1] = ntload4(tv4 + idx);
                #pragma unroll
                for (int k = 0; k < K; ++k) {
                    const size_t off = (size_t)k * (size_t)B4;
                    buf[u][2 + 3 * k] = ntload4(mu4 + off + idx);
                    buf[u][3 + 3 * k] = ntload4(sg4 + off + idx);
                    buf[u][4 + 3 * k] = ntload4(wt4 + off + idx);
                }
            }
            process_group_buf<K>(buf[0], bce, ll, npaid);
            process_group_buf<K>(buf[1], bce, ll, npaid);
        }
        // remaining single groups
        for (; i < B4; i += stride) {
            v4f buf[NB];
            buf[0] = ntload4(p4  + i);
            buf[1] = ntload4(tv4 + i);
            #pragma unroll
            for (int k = 0; k < K; ++k) {
                const size_t off = (size_t)k * (size_t)B4;
                buf[2 + 3 * k] = ntload4(mu4 + off + i);
                buf[3 + 3 * k] = ntload4(sg4 + off + i);
                buf[4 + 3 * k] = ntload4(wt4 + off + i);
            }
            process_group_buf<K>(buf, bce, ll, npaid);
        }
    } else {
        for (int i = tid; i < B; i += stride) {
            process_elem<K>(p[i], tv[i], mu, sigma, weight,
                            (size_t)i, (size_t)B, bce, ll, npaid);
        }
    }

    // wave-level reduction (wave = 64 lanes)
    #pragma unroll
    for (int off = 32; off > 0; off >>= 1) {
        bce   += __shfl_down(bce,   off, 64);
        ll    += __shfl_down(ll,    off, 64);
        npaid += __shfl_down(npaid, off, 64);
    }

    __shared__ float sdata[3][4];
    const int wave = threadIdx.x >> 6;
    const int lane = threadIdx.x & 63;
    if (lane == 0) {
        sdata[0][wave] = bce;
        sdata[1][wave] = ll;
        sdata[2][wave] = npaid;
    }
    __syncthreads();
    if (threadIdx.x == 0) {
        float b = 0.0f, l = 0.0f, n = 0.0f;
        #pragma unroll
        for (int w = 0; w < 4; ++w) {
            b += sdata[0][w];
            l += sdata[1][w];
            n += sdata[2][w];
        }
        part_bce[blockIdx.x] = b;
        part_ll [blockIdx.x] = l;
        part_n  [blockIdx.x] = n;
    }
}

__global__ __launch_bounds__(256) void zimol_reduce(
    const float* __restrict__ part_bce,
    const float* __restrict__ part_ll,
    const float* __restrict__ part_n,
    float* __restrict__ out, int nblocks, int B)
{
    double b = 0.0, l = 0.0, n = 0.0;
    for (int i = threadIdx.x; i < nblocks; i += 256) {
        b += (double)part_bce[i];
        l += (double)part_ll[i];
        n += (double)part_n[i];
    }
    #pragma unroll
    for (int off = 32; off > 0; off >>= 1) {
        b += __shfl_down(b, off, 64);
        l += __shfl_down(l, off, 64);
        n += __shfl_down(n, off, 64);
    }
    __shared__ double sdata[3][4];
    const int wave = threadIdx.x >> 6;
    const int lane = threadIdx.x & 63;
    if (lane == 0) {
        sdata[0][wave] = b;
        sdata[1][wave] = l;
        sdata[2][wave] = n;
    }
    __syncthreads();
    if (threadIdx.x == 0) {
        double tb = 0.0, tl = 0.0, tn = 0.0;
        #pragma unroll
        for (int w = 0; w < 4; ++w) {
            tb += sdata[0][w];
            tl += sdata[1][w];
            tn += sdata[2][w];
        }
        double purchase = tb / (double)B;
        double ltv = (tn > 0.0) ? -(tl / fmax(tn, 1.0)) : 0.0;
        out[0] = (float)(purchase + ltv);
    }
}

extern "C" void kernel_launch(void* const* d_in, const int* in_sizes, int n_in,
                              void* d_out, int out_size, void* d_ws, size_t ws_size,
                              hipStream_t stream) {
    const float* p      = (const float*)d_in[0];
    const float* mu     = (const float*)d_in[1];
    const float* sigma  = (const float*)d_in[2];
    const float* weight = (const float*)d_in[3];
    const float* tv     = (const float*)d_in[4];
    float* out = (float*)d_out;

    const int B = in_sizes[0];
    const int K = in_sizes[1] / B;

    const int threads = 256;
    // 1024 blocks (R3 best-graded config).
    int work = ((B + 3) >> 2);
    int blocks = (work + threads - 1) / threads;
    if (blocks > 1024) blocks = 1024;
    if (blocks < 1) blocks = 1;

    float* part_bce = (float*)d_ws;
    float* part_ll  = part_bce + blocks;
    float* part_n   = part_ll  + blocks;

    if (K == 3) {
        zimol_main<3><<<blocks, threads, 0, stream>>>(p, mu, sigma, weight, tv,
                                                      part_bce, part_ll, part_n, B);
    } else if (K == 1) {
        zimol_main<1><<<blocks, threads, 0, stream>>>(p, mu, sigma, weight, tv,
                                                      part_bce, part_ll, part_n, B);
    } else if (K == 2) {
        zimol_main<2><<<blocks, threads, 0, stream>>>(p, mu, sigma, weight, tv,
                                                      part_bce, part_ll, part_n, B);
    } else {
        zimol_main<4><<<blocks, threads, 0, stream>>>(p, mu, sigma, weight, tv,
                                                      part_bce, part_ll, part_n, B);
    }

    zimol_reduce<<<1, threads, 0, stream>>>(part_bce, part_ll, part_n, out, blocks, B);
}